// Round 1
// baseline (367.595 us; speedup 1.0000x reference)
//
#include <hip/hip_runtime.h>

// ---------------------------------------------------------------------------
// Transformer block (RMSNorm -> MHA(causal) -> proj+res -> RMSNorm -> GLU FFN)
// B=2 T=2048 D=1024 H=16 HD=64.  bf16 MFMA 16x16x32, f32 accumulate.
// All bf16 handled as unsigned short bit patterns.
// ---------------------------------------------------------------------------

typedef __attribute__((ext_vector_type(4))) float f32x4;
typedef __attribute__((ext_vector_type(8))) short short8;

typedef __attribute__((address_space(1))) const void gvoid;
typedef __attribute__((address_space(3))) void lvoid;

static __device__ __forceinline__ void gl_lds16(const void* g, void* l) {
  __builtin_amdgcn_global_load_lds((gvoid*)g, (lvoid*)l, 16, 0, 0);
}

static __device__ __forceinline__ unsigned short f2bf(float f) {
  union { float f; unsigned u; } v; v.f = f;
  unsigned r = v.u + 0x7fffu + ((v.u >> 16) & 1u);   // RNE
  return (unsigned short)(r >> 16);
}
static __device__ __forceinline__ float to_f32(float v) { return v; }
static __device__ __forceinline__ float to_f32(unsigned short v) {
  union { unsigned u; float f; } x; x.u = ((unsigned)v) << 16; return x.f;
}

static __device__ __forceinline__ f32x4 mfma16(short8 a, short8 b, f32x4 c) {
  return __builtin_amdgcn_mfma_f32_16x16x32_bf16(a, b, c, 0, 0, 0);
}

// ---------------------------------------------------------------------------
// Batched transpose + cvt to bf16: out[c][r] = (bf16) in[r][c]
// Grid: (C/64, R/64, batch). 256 threads.
// ---------------------------------------------------------------------------
template <typename Tin>
__global__ __launch_bounds__(256) void transpose_cvt(
    const Tin* __restrict__ in, unsigned short* __restrict__ out,
    int in_ld, long in_bstride, int out_ld, long out_bstride)
{
  __shared__ float tile[64][65];
  const Tin* inp = in + (long)blockIdx.z * in_bstride;
  unsigned short* outp = out + (long)blockIdx.z * out_bstride;
  int r0 = blockIdx.y * 64, c0 = blockIdx.x * 64;
  int tx = threadIdx.x & 63, ty = threadIdx.x >> 6;
#pragma unroll
  for (int i = ty; i < 64; i += 4)
    tile[i][tx] = to_f32(inp[(long)(r0 + i) * in_ld + (c0 + tx)]);
  __syncthreads();
#pragma unroll
  for (int i = ty; i < 64; i += 4)
    outp[(long)(c0 + i) * out_ld + (r0 + tx)] = f2bf(tile[tx][i]);
}

// ---------------------------------------------------------------------------
// RMSNorm row kernel: out_bf16[row] = x*rsqrt(mean(x^2)+eps)*g.  D=1024.
// ---------------------------------------------------------------------------
__global__ __launch_bounds__(256) void rmsnorm_k(
    const float* __restrict__ x, const float* __restrict__ g,
    unsigned short* __restrict__ out)
{
  int row = blockIdx.x;
  int t = threadIdx.x;
  float4 v = ((const float4*)(x + (long)row * 1024))[t];
  float ss = v.x * v.x + v.y * v.y + v.z * v.z + v.w * v.w;
#pragma unroll
  for (int ofs = 32; ofs; ofs >>= 1) ss += __shfl_down(ss, ofs);
  __shared__ float red[4];
  if ((t & 63) == 0) red[t >> 6] = ss;
  __syncthreads();
  float sc = rsqrtf((red[0] + red[1] + red[2] + red[3]) * (1.0f / 1024.0f) + 1e-6f);
  float4 gv = ((const float4*)g)[t];
  ushort4 o4;
  o4.x = f2bf(v.x * sc * gv.x); o4.y = f2bf(v.y * sc * gv.y);
  o4.z = f2bf(v.z * sc * gv.z); o4.w = f2bf(v.w * sc * gv.w);
  ((ushort4*)(out + (long)row * 1024))[t] = o4;
}

// ---------------------------------------------------------------------------
// GEMM: C[M][N] = A[M][K] * Bt[N][K]^T, 128x128 tile, BK=64, 256 threads.
// LDS staged via global_load_lds(16B) with pre-swizzled source (u ^= row&7 on
// 16B units) so ds_read_b128 fragment reads are bank-conflict-free.
// EPI: 0 = bf16 store (QKV), 1 = f32 res+bias (proj/FFN2), 2 = GLU pair->bf16.
// GLUB: B rows split 64 a-rows + 64 b-rows (w1t rows n and 4096+n).
// ---------------------------------------------------------------------------
template <int EPI, int WM_, int WN_, bool GLUB>
__global__ __launch_bounds__(256, 2) void gemm_bt(
    const unsigned short* __restrict__ A, const unsigned short* __restrict__ Bt,
    unsigned short* __restrict__ outb, float* __restrict__ outf,
    const float* __restrict__ res, const float* __restrict__ bias,
    int K, int lda, int ldbt, int ldout)
{
  constexpr int FM = 128 / (16 * WM_);
  constexpr int FN = 128 / (16 * WN_);
  __shared__ alignas(16) unsigned short Asm_[128 * 64];
  __shared__ alignas(16) unsigned short Bsm_[128 * 64];
  const int tid = threadIdx.x, lane = tid & 63, wave = tid >> 6;
  const int lr = lane & 15, lg = lane >> 4;
  const int wr = wave / WN_, wc = wave % WN_;
  const int m0 = blockIdx.y * 128;

  f32x4 acc[FM][FN];
#pragma unroll
  for (int mi = 0; mi < FM; mi++)
#pragma unroll
    for (int ni = 0; ni < FN; ni++) acc[mi][ni] = f32x4{0.f, 0.f, 0.f, 0.f};

  int arow[4], au[4];
  long brow[4];
#pragma unroll
  for (int i = 0; i < 4; i++) {
    int U = tid + 256 * i;
    arow[i] = U >> 3;
    au[i] = ((U & 7) ^ (arow[i] & 7)) * 8;   // swizzled source elem offset
    if (GLUB)
      brow[i] = (arow[i] < 64) ? (long)(blockIdx.x * 64 + arow[i])
                               : (long)(4096 + blockIdx.x * 64 + arow[i] - 64);
    else
      brow[i] = (long)blockIdx.x * 128 + arow[i];
  }

  for (int k0 = 0; k0 < K; k0 += 64) {
#pragma unroll
    for (int i = 0; i < 4; i++) {
      gl_lds16(A + (long)(m0 + arow[i]) * lda + k0 + au[i],
               (char*)Asm_ + (wave * 64 + 256 * i) * 16);
      gl_lds16(Bt + brow[i] * ldbt + k0 + au[i],
               (char*)Bsm_ + (wave * 64 + 256 * i) * 16);
    }
    __syncthreads();

    short8 af[FM][2], bfr[FN][2];
#pragma unroll
    for (int mi = 0; mi < FM; mi++) {
      int row = wr * 16 * FM + mi * 16 + lr;
#pragma unroll
      for (int kk = 0; kk < 2; kk++) {
        int off = row * 128 + (((kk * 4 + lg) ^ (row & 7)) * 16);
        af[mi][kk] = *(const short8*)((const char*)Asm_ + off);
      }
    }
#pragma unroll
    for (int ni = 0; ni < FN; ni++) {
      int row = wc * 16 * FN + ni * 16 + lr;
#pragma unroll
      for (int kk = 0; kk < 2; kk++) {
        int off = row * 128 + (((kk * 4 + lg) ^ (row & 7)) * 16);
        bfr[ni][kk] = *(const short8*)((const char*)Bsm_ + off);
      }
    }
#pragma unroll
    for (int kk = 0; kk < 2; kk++)
#pragma unroll
      for (int mi = 0; mi < FM; mi++)
#pragma unroll
        for (int ni = 0; ni < FN; ni++)
          acc[mi][ni] = mfma16(af[mi][kk], bfr[ni][kk], acc[mi][ni]);
    __syncthreads();
  }

  const int rb = m0 + wr * 16 * FM + 4 * lg;
  if constexpr (EPI == 0) {
#pragma unroll
    for (int mi = 0; mi < FM; mi++)
#pragma unroll
      for (int ni = 0; ni < FN; ni++) {
        int col = blockIdx.x * 128 + wc * 16 * FN + ni * 16 + lr;
#pragma unroll
        for (int r = 0; r < 4; r++)
          outb[(long)(rb + mi * 16 + r) * ldout + col] = f2bf(acc[mi][ni][r]);
      }
  } else if constexpr (EPI == 1) {
#pragma unroll
    for (int mi = 0; mi < FM; mi++)
#pragma unroll
      for (int ni = 0; ni < FN; ni++) {
        int col = blockIdx.x * 128 + wc * 16 * FN + ni * 16 + lr;
        float bv = bias[col];
#pragma unroll
        for (int r = 0; r < 4; r++) {
          long idx = (long)(rb + mi * 16 + r) * ldout + col;
          outf[idx] = acc[mi][ni][r] + res[idx] + bv;
        }
      }
  } else {  // GLU: pair (a = acc[ni], b = acc[ni+FN/2]) -> a*sigmoid(b), bf16
#pragma unroll
    for (int mi = 0; mi < FM; mi++)
#pragma unroll
      for (int ni = 0; ni < FN / 2; ni++) {
        int col = blockIdx.x * 64 + ni * 16 + lr;
        float ba = bias[col], bb = bias[4096 + col];
#pragma unroll
        for (int r = 0; r < 4; r++) {
          float a = acc[mi][ni][r] + ba;
          float b = acc[mi][ni + FN / 2][r] + bb;
          float s = 1.0f / (1.0f + __expf(-b));
          outb[(long)(rb + mi * 16 + r) * ldout + col] = f2bf(a * s);
        }
      }
  }
}

// ---------------------------------------------------------------------------
// Flash attention, causal. Grid (T/64, B*H). 4 waves; wave w owns q-rows
// [t0+16w, t0+16w+16). KVBLK=64. Q in regs; K and V^T chunks staged to LDS
// via swizzled-source global_load_lds; P redistributed via per-wave LDS.
// qkv: [B*T][3072] bf16 (q|k|v), vt: [B*H][64][2048] bf16, o: [B*T][1024].
// ---------------------------------------------------------------------------
__global__ __launch_bounds__(256, 2) void attn_k(
    const unsigned short* __restrict__ qkv, const unsigned short* __restrict__ vt,
    unsigned short* __restrict__ o)
{
  __shared__ alignas(16) unsigned short Ksm[64 * 64];
  __shared__ alignas(16) unsigned short Vsm[64 * 64];
  __shared__ alignas(16) unsigned short Psm[4][16 * 64];
  const int tid = threadIdx.x, lane = tid & 63, wave = tid >> 6;
  const int lr = lane & 15, lg = lane >> 4;
  const int t0 = blockIdx.x * 64, bh = blockIdx.y, b = bh >> 4, h = bh & 15;
  const float NEGINF = -__builtin_inff();

  short8 qf[2];
  {
    const unsigned short* qp =
        qkv + (long)(b * 2048 + t0 + wave * 16 + lr) * 3072 + h * 64 + lg * 8;
    qf[0] = *(const short8*)qp;
    qf[1] = *(const short8*)(qp + 32);
  }
  f32x4 o_acc[4];
#pragma unroll
  for (int n = 0; n < 4; n++) o_acc[n] = f32x4{0.f, 0.f, 0.f, 0.f};
  float mrow[4] = {NEGINF, NEGINF, NEGINF, NEGINF};
  float lsum[4] = {0.f, 0.f, 0.f, 0.f};

  const long kbase = (long)(b * 2048) * 3072 + 1024 + h * 64;
  const long vbase = (long)bh * 64 * 2048;
  int srow[2], su[2];
#pragma unroll
  for (int i = 0; i < 2; i++) {
    int U = tid + 256 * i;
    srow[i] = U >> 3;
    su[i] = ((U & 7) ^ (srow[i] & 7)) * 8;
  }

  const int nch = t0 / 64 + 1;
  for (int c = 0; c < nch; c++) {
    const int s0 = c * 64;
#pragma unroll
    for (int i = 0; i < 2; i++) {
      gl_lds16(qkv + kbase + (long)(s0 + srow[i]) * 3072 + su[i],
               (char*)Ksm + (wave * 64 + 256 * i) * 16);
      gl_lds16(vt + vbase + (long)srow[i] * 2048 + s0 + su[i],
               (char*)Vsm + (wave * 64 + 256 * i) * 16);
    }
    __syncthreads();

    f32x4 s_acc[4];
#pragma unroll
    for (int n = 0; n < 4; n++) s_acc[n] = f32x4{0.f, 0.f, 0.f, 0.f};
#pragma unroll
    for (int n = 0; n < 4; n++) {
      int row = n * 16 + lr;
#pragma unroll
      for (int kk = 0; kk < 2; kk++) {
        int off = row * 128 + (((kk * 4 + lg) ^ (row & 7)) * 16);
        short8 kf = *(const short8*)((const char*)Ksm + off);
        s_acc[n] = mfma16(qf[kk], kf, s_acc[n]);
      }
    }

    float pv[4][4];
    const int tq4 = t0 + wave * 16 + 4 * lg;
    const bool diag = (s0 == t0);
#pragma unroll
    for (int n = 0; n < 4; n++)
#pragma unroll
      for (int r = 0; r < 4; r++) {
        float v = s_acc[n][r] * 0.125f;
        if (diag && (s0 + n * 16 + lr > tq4 + r)) v = NEGINF;
        pv[n][r] = v;
      }
    float rmax[4];
#pragma unroll
    for (int r = 0; r < 4; r++)
      rmax[r] = fmaxf(fmaxf(pv[0][r], pv[1][r]), fmaxf(pv[2][r], pv[3][r]));
#pragma unroll
    for (int ofs = 1; ofs < 16; ofs <<= 1)
#pragma unroll
      for (int r = 0; r < 4; r++) rmax[r] = fmaxf(rmax[r], __shfl_xor(rmax[r], ofs));
    float alpha[4];
#pragma unroll
    for (int r = 0; r < 4; r++) {
      float mn = fmaxf(mrow[r], rmax[r]);
      alpha[r] = __expf(mrow[r] - mn);
      mrow[r] = mn;
    }
    float rsum[4] = {0.f, 0.f, 0.f, 0.f};
#pragma unroll
    for (int n = 0; n < 4; n++)
#pragma unroll
      for (int r = 0; r < 4; r++) {
        float p = __expf(pv[n][r] - mrow[r]);
        pv[n][r] = p;
        rsum[r] += p;
      }
#pragma unroll
    for (int ofs = 1; ofs < 16; ofs <<= 1)
#pragma unroll
      for (int r = 0; r < 4; r++) rsum[r] += __shfl_xor(rsum[r], ofs);
#pragma unroll
    for (int r = 0; r < 4; r++) lsum[r] = lsum[r] * alpha[r] + rsum[r];
#pragma unroll
    for (int n = 0; n < 4; n++)
#pragma unroll
      for (int r = 0; r < 4; r++) o_acc[n][r] *= alpha[r];

    // P -> per-wave LDS (swizzled), then read back as A-fragments
    char* pb = (char*)&Psm[wave][0];
#pragma unroll
    for (int n = 0; n < 4; n++)
#pragma unroll
      for (int r = 0; r < 4; r++) {
        int qrow = 4 * lg + r;
        int byte = qrow * 128 + ((((n * 16 + lr) * 2)) ^ ((qrow & 7) << 4));
        *(unsigned short*)(pb + byte) = f2bf(pv[n][r]);
      }
    asm volatile("s_waitcnt lgkmcnt(0)" ::: "memory");
    __builtin_amdgcn_sched_barrier(0);

    short8 pa[2];
#pragma unroll
    for (int kk = 0; kk < 2; kk++) {
      int off = lr * 128 + (((kk * 4 + lg) ^ (lr & 7)) * 16);
      pa[kk] = *(const short8*)(pb + off);
    }
#pragma unroll
    for (int n = 0; n < 4; n++) {
      int row = n * 16 + lr;
#pragma unroll
      for (int kk = 0; kk < 2; kk++) {
        int off = row * 128 + (((kk * 4 + lg) ^ (row & 7)) * 16);
        short8 vf = *(const short8*)((const char*)Vsm + off);
        o_acc[n] = mfma16(pa[kk], vf, o_acc[n]);
      }
    }
    __syncthreads();
  }

#pragma unroll
  for (int n = 0; n < 4; n++)
#pragma unroll
    for (int r = 0; r < 4; r++) {
      int trow = t0 + wave * 16 + 4 * lg + r;
      o[(long)(b * 2048 + trow) * 1024 + h * 64 + n * 16 + lr] =
          f2bf(o_acc[n][r] / lsum[r]);
    }
}

// ---------------------------------------------------------------------------
extern "C" void kernel_launch(void* const* d_in, const int* in_sizes, int n_in,
                              void* d_out, int out_size, void* d_ws, size_t ws_size,
                              hipStream_t stream) {
  const float* x     = (const float*)d_in[0];
  const float* wq    = (const float*)d_in[1];
  const float* wk    = (const float*)d_in[2];
  const float* wv    = (const float*)d_in[3];
  const float* wproj = (const float*)d_in[4];
  const float* bproj = (const float*)d_in[5];
  const float* w1    = (const float*)d_in[6];
  const float* b1    = (const float*)d_in[7];
  const float* w2    = (const float*)d_in[8];
  const float* b2    = (const float*)d_in[9];
  const float* g1    = (const float*)d_in[10];
  const float* g2    = (const float*)d_in[11];
  (void)in_sizes; (void)n_in; (void)out_size; (void)ws_size;

  char* ws = (char*)d_ws;
  unsigned short* wt_qkv = (unsigned short*)(ws);                    // 6 MB [3072][1024]
  unsigned short* wpt    = (unsigned short*)(ws + (6ul << 20));      // 2 MB [1024][1024]
  unsigned short* w1t    = (unsigned short*)(ws + (8ul << 20));      // 16 MB [8192][1024]
  unsigned short* w2t    = (unsigned short*)(ws + (24ul << 20));     // 8 MB [1024][4096]
  unsigned short* xn     = (unsigned short*)(ws + (32ul << 20));     // 8 MB [4096][1024]
  unsigned short* qkv    = (unsigned short*)(ws + (40ul << 20));     // 24 MB [4096][3072]
  unsigned short* vt     = (unsigned short*)(ws + (64ul << 20));     // 8 MB [32][64][2048]
  unsigned short* glu    = (unsigned short*)(ws + (40ul << 20));     // 32 MB alias (qkv+vt dead)
  unsigned short* obuf   = (unsigned short*)(ws + (72ul << 20));     // 8 MB [4096][1024]
  float*          x1     = (float*)(ws + (80ul << 20));              // 16 MB [4096][1024]
  float* outf = (float*)d_out;

  // --- weight repacks (f32 -> bf16, B^T layout) ---
  transpose_cvt<float><<<dim3(1, 16, 16), 256, 0, stream>>>(
      wq, wt_qkv, 64, (long)1024 * 64, 1024, (long)64 * 1024);
  transpose_cvt<float><<<dim3(1, 16, 16), 256, 0, stream>>>(
      wk, wt_qkv + 1024ul * 1024, 64, (long)1024 * 64, 1024, (long)64 * 1024);
  transpose_cvt<float><<<dim3(1, 16, 16), 256, 0, stream>>>(
      wv, wt_qkv + 2048ul * 1024, 64, (long)1024 * 64, 1024, (long)64 * 1024);
  transpose_cvt<float><<<dim3(16, 16, 1), 256, 0, stream>>>(
      wproj, wpt, 1024, 0, 1024, 0);
  transpose_cvt<float><<<dim3(128, 16, 1), 256, 0, stream>>>(
      w1, w1t, 8192, 0, 1024, 0);
  transpose_cvt<float><<<dim3(16, 64, 1), 256, 0, stream>>>(
      w2, w2t, 1024, 0, 4096, 0);

  // --- rmsnorm 1 ---
  rmsnorm_k<<<4096, 256, 0, stream>>>(x, g1, xn);

  // --- QKV GEMM: [4096,1024] x [1024,3072] -> qkv bf16 ---
  gemm_bt<0, 2, 2, false><<<dim3(24, 32), 256, 0, stream>>>(
      xn, wt_qkv, qkv, nullptr, nullptr, nullptr, 1024, 1024, 1024, 3072);

  // --- V^T per (b,h): [64][2048] ---
  transpose_cvt<unsigned short><<<dim3(1, 32, 16), 256, 0, stream>>>(
      qkv + 2048, vt, 3072, 64, 2048, (long)64 * 2048);
  transpose_cvt<unsigned short><<<dim3(1, 32, 16), 256, 0, stream>>>(
      qkv + 2048ul * 3072 + 2048, vt + 16ul * 64 * 2048, 3072, 64, 2048, (long)64 * 2048);

  // --- attention ---
  attn_k<<<dim3(32, 32), 256, 0, stream>>>(qkv, vt, obuf);

  // --- proj + residual + bias -> x1 (f32) ---
  gemm_bt<1, 2, 2, false><<<dim3(8, 32), 256, 0, stream>>>(
      obuf, wpt, nullptr, x1, x, bproj, 1024, 1024, 1024, 1024);

  // --- rmsnorm 2 ---
  rmsnorm_k<<<4096, 256, 0, stream>>>(x1, g2, xn);

  // --- FFN1 + GLU -> glu bf16 [4096][4096] ---
  gemm_bt<2, 4, 1, true><<<dim3(64, 32), 256, 0, stream>>>(
      xn, w1t, glu, nullptr, nullptr, b1, 1024, 1024, 1024, 4096);

  // --- FFN2 + residual + bias -> d_out (f32) ---
  gemm_bt<1, 2, 2, false><<<dim3(8, 32), 256, 0, stream>>>(
      glu, w2t, nullptr, outf, x1, b2, 4096, 4096, 4096, 1024);
}